// Round 1
// baseline (229.197 us; speedup 1.0000x reference)
//
#include <hip/hip_runtime.h>

#define BB 32
#define LL 1024
#define HH 384
#define H4 (HH / 4)   // 96 float4 per row
#define TT 64         // t-positions per block
#define NT 256        // threads per block

__global__ __launch_bounds__(NT) void lenreg_kernel(
    const float* __restrict__ ehs,   // (B, L, H) f32
    const int* __restrict__ dur,     // (B, L) i32
    float* __restrict__ out,         // (B, T, H) f32
    float* __restrict__ mask,        // (B, T) f32
    int T)
{
    __shared__ int scum[LL];     // inclusive cumsum of durations for this batch
    __shared__ int psum[NT];     // per-thread partial sums for the scan
    __shared__ int sidx[TT];     // source token index per t in this tile

    const int tid = threadIdx.x;
    const int b   = blockIdx.y;
    const int t0  = blockIdx.x * TT;

    // ---- block-level cumsum of durations[b, :] into LDS ----
    // each thread loads 4 consecutive durations
    int4 d = ((const int4*)(dur + (size_t)b * LL))[tid];
    int p0 = d.x;
    int p1 = p0 + d.y;
    int p2 = p1 + d.z;
    int p3 = p2 + d.w;
    psum[tid] = p3;
    __syncthreads();
    // Hillis-Steele inclusive scan over 256 partials
    #pragma unroll
    for (int off = 1; off < NT; off <<= 1) {
        int v = (tid >= off) ? psum[tid - off] : 0;
        __syncthreads();
        psum[tid] += v;
        __syncthreads();
    }
    const int excl = (tid > 0) ? psum[tid - 1] : 0;
    scum[4 * tid + 0] = excl + p0;
    scum[4 * tid + 1] = excl + p1;
    scum[4 * tid + 2] = excl + p2;
    scum[4 * tid + 3] = excl + p3;
    __syncthreads();

    const int total = scum[LL - 1];   // LDS broadcast

    // ---- binary search: idx[t] = #(cum <= t), clamped to L-1 ----
    if (tid < TT) {
        const int t = t0 + tid;
        int lo = 0, hi = LL;
        // exactly 10 iterations (L = 2^10); side='right' semantics
        while (lo < hi) {
            const int mid = (lo + hi) >> 1;
            if (scum[mid] <= t) lo = mid + 1; else hi = mid;
        }
        sidx[tid] = (lo < LL - 1) ? lo : (LL - 1);
        if (t < T) mask[(size_t)b * T + t] = (t < total) ? 1.0f : 0.0f;
    }
    __syncthreads();

    // ---- gather + store: TT t's x 96 float4, fully coalesced ----
    const float4* __restrict__ src_base = (const float4*)(ehs + (size_t)b * LL * HH);
    float4* __restrict__ out4 = (float4*)out;
    const float4 zero4 = make_float4(0.f, 0.f, 0.f, 0.f);

    for (int w = tid; w < TT * H4; w += NT) {
        const int tl = w / H4;          // which t in the tile (constant div -> magic mul)
        const int v  = w - tl * H4;     // which float4 within the row
        const int t  = t0 + tl;
        if (t >= T) break;              // t is non-decreasing in w for a given thread
        float4 val = zero4;
        if (t < total) {
            val = src_base[(size_t)sidx[tl] * H4 + v];
        }
        out4[((size_t)b * T + t) * H4 + v] = val;
    }
}

extern "C" void kernel_launch(void* const* d_in, const int* in_sizes, int n_in,
                              void* d_out, int out_size, void* d_ws, size_t ws_size,
                              hipStream_t stream) {
    const float* ehs = (const float*)d_in[0];
    const int*   dur = (const int*)d_in[1];

    // out_size = B*T*H + B*T = B*T*(H+1)
    const int T = out_size / (BB * (HH + 1));

    float* out  = (float*)d_out;
    float* mask = (float*)d_out + (size_t)BB * T * HH;

    dim3 grid((T + TT - 1) / TT, BB);
    dim3 block(NT);
    lenreg_kernel<<<grid, block, 0, stream>>>(ehs, dur, out, mask, T);
}